// Round 3
// baseline (1425.301 us; speedup 1.0000x reference)
//
#include <hip/hip_runtime.h>
#include <hip/hip_cooperative_groups.h>

namespace cg = cooperative_groups;

#define B_ 256
#define D_ 784
#define V_ 128
#define S_ 2
#define BD (B_ * D_)
#define KS 16      // K slices
#define KC 49      // 784 / 16

__device__ __forceinline__ double wave_red(double v) {
#pragma unroll
    for (int o = 32; o > 0; o >>= 1) v += __shfl_down(v, o, 64);
    return v;
}

// One cooperative kernel, 256 blocks x 1024 threads (1 block/CU).
// Phases separated by grid.sync():
//   init -> [ gemm(xf) -> forward -> gemm(xdf) -> reverse ] x 2 steps
// GEMM phase: block = (bt = blk>>4: 16 batch rows) x (kz = blk&15: 49-wide K slice).
// forward/reverse phase: block = batch row b. lpf/Exf/la live in shared (same block).
__global__ __launch_bounds__(1024, 4) void mega_k(
    const int* __restrict__ x, const float* __restrict__ W,
    const float* __restrict__ bv, const float* __restrict__ gum,
    const float* __restrict__ u, const int* __restrict__ kiter,
    float* __restrict__ wsym, int* __restrict__ x_cur,
    int* __restrict__ x_delta, float* __restrict__ xf,
    float* __restrict__ xdf, float* __restrict__ gpart,
    float* __restrict__ out)
{
    cg::grid_group grid = cg::this_grid();
    const int tid = threadIdx.x;
    const int blk = blockIdx.x;
    const int gstride = 256 * 1024;

    __shared__ float As[16][KC];
    __shared__ double wred[16];
    __shared__ double lpf_s, Exf_s;
    __shared__ int acc_s;
    __shared__ float la_s;

    // ---- phase 0: init (wsym, x_cur, xf) ----
    for (int gid = blk * 1024 + tid; gid < D_ * D_; gid += gstride) {
        int i = gid / D_, j = gid % D_;
        wsym[gid] = 0.5f * (W[gid] + W[j * D_ + i]);
    }
    for (int gid = blk * 1024 + tid; gid < BD; gid += gstride) {
        int xi = x[gid];
        x_cur[gid] = xi;
        xf[gid] = (float)xi;
    }
    const int kmod = kiter[0] % 10;
    const float ss  = (kmod == 0) ? 0.5f : 0.1f;
    const float bal = (kmod == 0) ? 0.9f : 0.6f;
    const float c2 = 0.5f / ss;

    const int bt = blk >> 4, kz = blk & 15;
    const int k0 = kz * KC;
    const int lane = tid & 63, wv = tid >> 6;

    __threadfence();
    grid.sync();

    for (int s = 0; s < S_; ++s) {
        // ---- GEMM1: gpart[kz][16 rows][784] = xf-tile @ wsym-slice ----
        {
            for (int idx = tid; idx < 16 * KC; idx += 1024) {
                int r = idx / KC, c = idx % KC;
                As[r][c] = xf[(bt * 16 + r) * D_ + k0 + c];
            }
            __syncthreads();
            if (tid < D_) {
                float acc[16] = {};
                for (int kk = 0; kk < KC; ++kk) {
                    float wval = wsym[(k0 + kk) * D_ + tid];
#pragma unroll
                    for (int i = 0; i < 16; ++i)
                        acc[i] = fmaf(As[i][kk], wval, acc[i]);
                }
#pragma unroll
                for (int i = 0; i < 16; ++i)
                    gpart[(size_t)kz * BD + (size_t)(bt * 16 + i) * D_ + tid] = acc[i];
            }
        }
        __threadfence();
        grid.sync();

        // ---- forward: windowed categorical + lse; block = b ----
        // logit lg(v) = a1*dv - c2*dv^2, concave; vertex v0 = xf + a1*ss.
        // Gumbel in [-2.626, 13.816] => deficit > 16.45 can't win argmax;
        // lse terms with drop > 41 are below fp32 ulp. Window: drop <= 41.
        {
            const int b = blk;
            double lp_acc = 0.0, e_acc = 0.0;
            if (tid < D_) {
                const int d = tid, bd = b * D_ + d;
                const int xi = x_cur[bd];
                const float xfv = (float)xi;
                float gv = 0.f;
#pragma unroll
                for (int p = 0; p < KS; ++p) gv += gpart[(size_t)p * BD + bd];
                gv += bv[d];
                const float a1 = bal * gv;
                const float v0 = xfv + a1 * ss;
                int vm = (int)rintf(v0); vm = min(127, max(0, vm));
                const float dmv = v0 - (float)vm;
                const float Reff = sqrtf(41.0f / c2 + dmv * dmv);
                int lo = max(0, (int)ceilf(v0 - Reff));
                int hi = min(127, (int)floorf(v0 + Reff));
                lo = min(lo, vm); hi = max(hi, vm);
                const float dvm = (float)vm - xfv;
                const float mL = dvm * fmaf(-c2, dvm, a1);
                const float* __restrict__ grow = gum + (((size_t)s * B_ + b) * D_ + d) * V_;
                float best = -1e30f; int imax = lo; float sum = 0.f;
                for (int v = lo; v <= hi; ++v) {
                    float dv = (float)v - xfv;
                    float lg = dv * fmaf(-c2, dv, a1);
                    float y = lg + grow[v];
                    if (y > best) { best = y; imax = v; }   // strict >: np.argmax first-max
                    sum += expf(lg - mL);
                }
                float lse = mL + logf(sum);
                float dvc = (float)imax - xfv;
                float lch = dvc * fmaf(-c2, dvc, a1);
                lp_acc = (double)(lch - lse);
                e_acc  = (double)xfv * ((double)gv + (double)bv[d]);
                x_delta[bd] = imax;
                xdf[bd] = (float)imax;
            }
            double t = wave_red(lp_acc);
            if (lane == 0) wred[wv] = t;
            __syncthreads();
            if (tid == 0) { double sm = 0; for (int i = 0; i < 16; ++i) sm += wred[i]; lpf_s = sm; }
            __syncthreads();
            t = wave_red(e_acc);
            if (lane == 0) wred[wv] = t;
            __syncthreads();
            if (tid == 0) { double sm = 0; for (int i = 0; i < 16; ++i) sm += wred[i]; Exf_s = sm; }
        }
        __threadfence();
        grid.sync();

        // ---- GEMM2 on xdf ----
        {
            for (int idx = tid; idx < 16 * KC; idx += 1024) {
                int r = idx / KC, c = idx % KC;
                As[r][c] = xdf[(bt * 16 + r) * D_ + k0 + c];
            }
            __syncthreads();
            if (tid < D_) {
                float acc[16] = {};
                for (int kk = 0; kk < KC; ++kk) {
                    float wval = wsym[(k0 + kk) * D_ + tid];
#pragma unroll
                    for (int i = 0; i < 16; ++i)
                        acc[i] = fmaf(As[i][kk], wval, acc[i]);
                }
#pragma unroll
                for (int i = 0; i < 16; ++i)
                    gpart[(size_t)kz * BD + (size_t)(bt * 16 + i) * D_ + tid] = acc[i];
            }
        }
        __threadfence();
        grid.sync();

        // ---- reverse + MH accept + update; block = b ----
        {
            const int b = blk;
            double lp_acc = 0.0, e_acc = 0.0;
            if (tid < D_) {
                const int d = tid, bd = b * D_ + d;
                const int xi = x_cur[bd];
                const int xd = x_delta[bd];
                const float xdv = (float)xd;
                float gv = 0.f;
#pragma unroll
                for (int p = 0; p < KS; ++p) gv += gpart[(size_t)p * BD + bd];
                gv += bv[d];
                const float a1 = bal * gv;
                const float v0 = xdv + a1 * ss;
                int vm = (int)rintf(v0); vm = min(127, max(0, vm));
                const float dmv = v0 - (float)vm;
                const float Reff = sqrtf(41.0f / c2 + dmv * dmv);
                int lo = max(0, (int)ceilf(v0 - Reff));
                int hi = min(127, (int)floorf(v0 + Reff));
                lo = min(lo, vm); hi = max(hi, vm);
                const float dvm = (float)vm - xdv;
                const float mL = dvm * fmaf(-c2, dvm, a1);
                float sum = 0.f;
                for (int v = lo; v <= hi; ++v) {
                    float dv = (float)v - xdv;
                    float lg = dv * fmaf(-c2, dv, a1);
                    sum += expf(lg - mL);
                }
                float lse = mL + logf(sum);
                float dvc = (float)xi - xdv;              // logp_d gathered at x_cur
                float lch = dvc * fmaf(-c2, dvc, a1);
                lp_acc = (double)(lch - lse);
                e_acc  = (double)xdv * ((double)gv + (double)bv[d]);
            }
            double t = wave_red(lp_acc);
            if (lane == 0) wred[wv] = t;
            __syncthreads();
            double lpr = 0;
            if (tid == 0) { for (int i = 0; i < 16; ++i) lpr += wred[i]; }
            __syncthreads();
            t = wave_red(e_acc);
            if (lane == 0) wred[wv] = t;
            __syncthreads();
            if (tid == 0) {
                double exd = 0; for (int i = 0; i < 16; ++i) exd += wred[i];
                double la = 0.5 * (exd - Exf_s) + lpr - lpf_s;
                acc_s = (exp(la) > (double)u[s * B_ + b]) ? 1 : 0;
                la_s = (float)la;
            }
            __syncthreads();
            const int acc = acc_s;
            if (tid < D_) {
                const int bd = b * D_ + tid;
                int xn = acc ? x_delta[bd] : x_cur[bd];
                x_cur[bd] = xn;
                xf[bd] = (float)xn;
                if (s == S_ - 1) out[bd] = (float)xn;
            }
            if (s == S_ - 1 && tid == 0) out[BD + b] = la_s;
        }
        __threadfence();
        grid.sync();
    }
}

// ---------------------------------------------------------------------------
extern "C" void kernel_launch(void* const* d_in, const int* in_sizes, int n_in,
                              void* d_out, int out_size, void* d_ws, size_t ws_size,
                              hipStream_t stream)
{
    const int*   x     = (const int*)d_in[0];
    const float* W     = (const float*)d_in[1];
    const float* bv    = (const float*)d_in[2];
    const float* gum   = (const float*)d_in[3];
    const float* u     = (const float*)d_in[4];
    const int*   kiter = (const int*)d_in[5];
    float* out = (float*)d_out;

    char* w = (char*)d_ws;
    size_t off = 0;
    auto carve = [&](size_t bytes) { void* p = w + off; off += (bytes + 511) & ~511ull; return p; };
    float* wsym    = (float*)carve((size_t)D_ * D_ * 4);
    int*   x_cur   = (int*)  carve((size_t)BD * 4);
    int*   x_delta = (int*)  carve((size_t)BD * 4);
    float* xf      = (float*)carve((size_t)BD * 4);
    float* xdf     = (float*)carve((size_t)BD * 4);
    float* gpart   = (float*)carve((size_t)KS * BD * 4);
    (void)ws_size; (void)in_sizes; (void)n_in; (void)out_size;

    void* args[] = {
        (void*)&x, (void*)&W, (void*)&bv, (void*)&gum, (void*)&u, (void*)&kiter,
        (void*)&wsym, (void*)&x_cur, (void*)&x_delta, (void*)&xf, (void*)&xdf,
        (void*)&gpart, (void*)&out
    };
    hipLaunchCooperativeKernel((const void*)mega_k, dim3(256), dim3(1024),
                               args, 0, stream);
}

// Round 4
// 403.083 us; speedup vs baseline: 3.5360x; 3.5360x over previous
//
#include <hip/hip_runtime.h>

#define B_ 256
#define D_ 784
#define V_ 128
#define S_ 2
#define BD (B_ * D_)
#define KSPLIT 4
#define KC 196     // 784 / KSPLIT

__device__ __forceinline__ void get_params(const int* kiter, float& ss, float& bal) {
    int k = kiter[0] % 10;
    ss  = (k == 0) ? 0.5f : 0.1f;
    bal = (k == 0) ? 0.9f : 0.6f;
}

__device__ __forceinline__ double wave_red(double v) {
#pragma unroll
    for (int o = 32; o > 0; o >>= 1) v += __shfl_down(v, o, 64);
    return v;
}

// ---------------------------------------------------------------------------
// init: Wsym = 0.5*(W + W^T); x_cur = x; xf = float(x)
// ---------------------------------------------------------------------------
__global__ __launch_bounds__(256) void init_k(
    const float* __restrict__ W, const int* __restrict__ x,
    float* __restrict__ wsym, int* __restrict__ x_cur, float* __restrict__ xf)
{
    int gid = blockIdx.x * 256 + threadIdx.x;
    if (gid < D_ * D_) {
        int i = gid / D_, j = gid % D_;
        wsym[gid] = 0.5f * (W[gid] + W[j * D_ + i]);
    }
    if (gid < BD) {
        int xi = x[gid];
        x_cur[gid] = xi;
        xf[gid] = (float)xi;
    }
}

// ---------------------------------------------------------------------------
// split-K fp32 GEMM: Cpart[kz][b][d] = sum_{k in slice kz} A[b][k]*Wsym[k][d]
// 64x64 tiles, kc=16, KSPLIT=4 (196 K each). Deterministic.
// ---------------------------------------------------------------------------
__global__ __launch_bounds__(256) void gemm_splitk(
    const float* __restrict__ A, const float* __restrict__ Wm,
    float* __restrict__ Cp)
{
    const int bt = blockIdx.x, dt = blockIdx.y, kz = blockIdx.z;
    const int tid = threadIdx.x;
    const int k0 = kz * KC, kend = k0 + KC;

    __shared__ float As[64][17];
    __shared__ float Ws[16][65];

    const int tx = tid & 15, ty = tid >> 4;
    const int arow = tid >> 2, ac0 = (tid & 3) * 4;
    const int wrow = tid >> 4, wc0 = (tid & 15) * 4;

    float acc[4][4] = {};

    for (int kb = k0; kb < kend; kb += 16) {
#pragma unroll
        for (int c = 0; c < 4; ++c) {
            int k = kb + ac0 + c;
            As[arow][ac0 + c] = (k < kend) ? A[(bt * 64 + arow) * D_ + k] : 0.f;
        }
#pragma unroll
        for (int c = 0; c < 4; ++c) {
            int k = kb + wrow;
            int d = dt * 64 + wc0 + c;
            Ws[wrow][wc0 + c] = (k < kend && d < D_) ? Wm[k * D_ + d] : 0.f;
        }
        __syncthreads();
#pragma unroll
        for (int kk = 0; kk < 16; ++kk) {
            float a[4], w[4];
#pragma unroll
            for (int i = 0; i < 4; ++i) a[i] = As[ty * 4 + i][kk];
#pragma unroll
            for (int j = 0; j < 4; ++j) w[j] = Ws[kk][tx * 4 + j];
#pragma unroll
            for (int i = 0; i < 4; ++i)
#pragma unroll
                for (int j = 0; j < 4; ++j)
                    acc[i][j] = fmaf(a[i], w[j], acc[i][j]);
        }
        __syncthreads();
    }

#pragma unroll
    for (int i = 0; i < 4; ++i) {
        int bb = bt * 64 + ty * 4 + i;
#pragma unroll
        for (int j = 0; j < 4; ++j) {
            int d = dt * 64 + tx * 4 + j;
            if (d < D_) Cp[(size_t)kz * BD + (size_t)bb * D_ + d] = acc[i][j];
        }
    }
}

// ---------------------------------------------------------------------------
// forward: fused g-reduce + windowed categorical + lse.
// lg(v) = a1*dv - c2*dv^2 concave, vertex v0 = xf + a1*ss. Gumbel range
// [-2.626, 13.816] => deficit > 16.45 can't win argmax; lse tail at drop>30
// is < 1.2e-11 relative. Window: drop <= 30 => span <= 12 values <= 4 quads.
// Gumbel read as 4 aligned float4 loads issued up-front (no serial chain).
// ---------------------------------------------------------------------------
__global__ __launch_bounds__(1024) void forward_k(
    const int* __restrict__ x_cur, const float* __restrict__ gpart,
    const float* __restrict__ bvec, const float* __restrict__ gumbel,
    const int* __restrict__ kiter, int s,
    int* __restrict__ x_delta, float* __restrict__ xdf,
    double* __restrict__ lpf, double* __restrict__ Exf)
{
    const int b = blockIdx.x, tid = threadIdx.x;
    float ss, bal; get_params(kiter, ss, bal);
    const float c2 = 0.5f / ss;

    double lp_acc = 0.0, e_acc = 0.0;

    if (tid < D_) {
        const int d = tid, bd = b * D_ + d;
        const int xi = x_cur[bd];
        const float xfv = (float)xi;

        float gv = 0.f;
#pragma unroll
        for (int p = 0; p < KSPLIT; ++p) gv += gpart[(size_t)p * BD + bd];
        gv += bvec[d];

        const float a1 = bal * gv;
        const float v0 = xfv + a1 * ss;
        int vm = (int)rintf(v0); vm = min(127, max(0, vm));
        const float dmv = v0 - (float)vm;
        const float Reff = sqrtf(30.0f / c2 + dmv * dmv);
        int lo = max(0, (int)ceilf(v0 - Reff));
        int hi = min(127, (int)floorf(v0 + Reff));
        lo = min(lo, vm); hi = max(hi, vm);

        const float dvm = (float)vm - xfv;
        const float mL = dvm * fmaf(-c2, dvm, a1);   // exact max logit (concavity)

        const float4* __restrict__ gq =
            (const float4*)(gumbel + (((size_t)s * B_ + b) * D_ + d) * V_);
        const int q0 = lo >> 2;
        float4 quad[4];
#pragma unroll
        for (int j = 0; j < 4; ++j) quad[j] = gq[min(q0 + j, 31)];   // batch-issued

        float best = -1e30f; int imax = vm;
        float sum0 = 0.f, sum1 = 0.f;
#pragma unroll
        for (int j = 0; j < 4; ++j) {
            const int qi = q0 + j;
            const bool qok = qi < 32;
            const float qs[4] = {quad[j].x, quad[j].y, quad[j].z, quad[j].w};
#pragma unroll
            for (int c = 0; c < 4; ++c) {
                int v = 4 * qi + c;
                bool ok = qok && v >= lo && v <= hi;
                float dv = (float)v - xfv;
                float lg = dv * fmaf(-c2, dv, a1);
                float y = ok ? (lg + qs[c]) : -1e30f;
                if (y > best) { best = y; imax = v; }   // ascending v, strict >: np.argmax
                float e = expf(lg - mL);
                if (c & 1) sum1 += ok ? e : 0.f; else sum0 += ok ? e : 0.f;
            }
        }
        float lse = mL + logf(sum0 + sum1);
        float dvc = (float)imax - xfv;
        float lch = dvc * fmaf(-c2, dvc, a1);
        lp_acc = (double)(lch - lse);
        e_acc  = (double)xfv * ((double)gv + (double)bvec[d]);
        x_delta[bd] = imax;
        xdf[bd] = (float)imax;
    }

    __shared__ double wred[16];
    const int lane = tid & 63, wv = tid >> 6;
    double t = wave_red(lp_acc);
    if (lane == 0) wred[wv] = t;
    __syncthreads();
    if (tid == 0) { double sm = 0; for (int i = 0; i < 16; ++i) sm += wred[i]; lpf[b] = sm; }
    __syncthreads();
    t = wave_red(e_acc);
    if (lane == 0) wred[wv] = t;
    __syncthreads();
    if (tid == 0) { double sm = 0; for (int i = 0; i < 16; ++i) sm += wred[i]; Exf[b] = sm; }
}

// ---------------------------------------------------------------------------
// reverse: fused g-reduce + windowed lse (no gumbel) + MH accept + update.
// ---------------------------------------------------------------------------
__global__ __launch_bounds__(1024) void reverse_k(
    int* __restrict__ x_cur, const int* __restrict__ x_delta,
    const float* __restrict__ gpart, const float* __restrict__ bvec,
    const float* __restrict__ u, const int* __restrict__ kiter,
    int s, int last, const double* __restrict__ lpf, const double* __restrict__ Exf,
    float* __restrict__ xf_f, float* __restrict__ out)
{
    const int b = blockIdx.x, tid = threadIdx.x;
    float ss, bal; get_params(kiter, ss, bal);
    const float c2 = 0.5f / ss;

    double lp_acc = 0.0, e_acc = 0.0;

    if (tid < D_) {
        const int d = tid, bd = b * D_ + d;
        const int xi = x_cur[bd];
        const int xd = x_delta[bd];
        const float xdv = (float)xd;

        float gv = 0.f;
#pragma unroll
        for (int p = 0; p < KSPLIT; ++p) gv += gpart[(size_t)p * BD + bd];
        gv += bvec[d];

        const float a1 = bal * gv;
        const float v0 = xdv + a1 * ss;
        int vm = (int)rintf(v0); vm = min(127, max(0, vm));
        const float dmv = v0 - (float)vm;
        const float Reff = sqrtf(30.0f / c2 + dmv * dmv);
        int lo = max(0, (int)ceilf(v0 - Reff));
        int hi = min(127, (int)floorf(v0 + Reff));
        lo = min(lo, vm); hi = max(hi, vm);

        const float dvm = (float)vm - xdv;
        const float mL = dvm * fmaf(-c2, dvm, a1);
        float sum0 = 0.f, sum1 = 0.f;
#pragma unroll
        for (int j = 0; j < 16; ++j) {       // span <= 12, predicated, full ILP
            int v = lo + j;
            bool ok = v <= hi;
            float dv = (float)v - xdv;
            float lg = dv * fmaf(-c2, dv, a1);
            float e = expf(lg - mL);
            if (j & 1) sum1 += ok ? e : 0.f; else sum0 += ok ? e : 0.f;
        }
        float lse = mL + logf(sum0 + sum1);
        float dvc = (float)xi - xdv;                 // logp_d gathered at x_cur
        float lch = dvc * fmaf(-c2, dvc, a1);
        lp_acc = (double)(lch - lse);
        e_acc  = (double)xdv * ((double)gv + (double)bvec[d]);
    }

    __shared__ double wred[16];
    __shared__ int accept_s;
    __shared__ float la_s;
    const int lane = tid & 63, wv = tid >> 6;

    double t = wave_red(lp_acc);
    if (lane == 0) wred[wv] = t;
    __syncthreads();
    double lpr = 0;
    if (tid == 0) { for (int i = 0; i < 16; ++i) lpr += wred[i]; }
    __syncthreads();
    t = wave_red(e_acc);
    if (lane == 0) wred[wv] = t;
    __syncthreads();
    if (tid == 0) {
        double exd = 0; for (int i = 0; i < 16; ++i) exd += wred[i];
        double la = 0.5 * (exd - Exf[b]) + lpr - lpf[b];
        accept_s = (exp(la) > (double)u[s * B_ + b]) ? 1 : 0;
        la_s = (float)la;
    }
    __syncthreads();

    const int acc = accept_s;
    if (tid < D_) {
        const int bd = b * D_ + tid;
        int xn = acc ? x_delta[bd] : x_cur[bd];
        x_cur[bd] = xn;
        xf_f[bd] = (float)xn;
        if (last) out[bd] = (float)xn;
    }
    if (last && tid == 0) out[BD + b] = la_s;
}

// ---------------------------------------------------------------------------
extern "C" void kernel_launch(void* const* d_in, const int* in_sizes, int n_in,
                              void* d_out, int out_size, void* d_ws, size_t ws_size,
                              hipStream_t stream)
{
    const int*   x     = (const int*)d_in[0];
    const float* W     = (const float*)d_in[1];
    const float* bv    = (const float*)d_in[2];
    const float* gum   = (const float*)d_in[3];
    const float* u     = (const float*)d_in[4];
    const int*   kiter = (const int*)d_in[5];
    float* out = (float*)d_out;

    char* w = (char*)d_ws;
    size_t off = 0;
    auto carve = [&](size_t bytes) { void* p = w + off; off += (bytes + 511) & ~511ull; return p; };
    float*  wsym    = (float*)carve((size_t)D_ * D_ * 4);
    int*    x_cur   = (int*)  carve((size_t)BD * 4);
    int*    x_delta = (int*)  carve((size_t)BD * 4);
    float*  xf      = (float*)carve((size_t)BD * 4);
    float*  xdf     = (float*)carve((size_t)BD * 4);
    float*  gpart   = (float*)carve((size_t)KSPLIT * BD * 4);
    double* lpf     = (double*)carve(B_ * 8);
    double* Exf     = (double*)carve(B_ * 8);
    (void)ws_size; (void)in_sizes; (void)n_in; (void)out_size;

    init_k<<<(D_ * D_ + 255) / 256, 256, 0, stream>>>(W, x, wsym, x_cur, xf);

    for (int s = 0; s < S_; ++s) {
        gemm_splitk<<<dim3(4, 13, KSPLIT), 256, 0, stream>>>(xf, wsym, gpart);
        forward_k<<<B_, 1024, 0, stream>>>(x_cur, gpart, bv, gum, kiter, s,
                                           x_delta, xdf, lpf, Exf);
        gemm_splitk<<<dim3(4, 13, KSPLIT), 256, 0, stream>>>(xdf, wsym, gpart);
        reverse_k<<<B_, 1024, 0, stream>>>(x_cur, x_delta, gpart, bv, u, kiter, s,
                                           (s == S_ - 1) ? 1 : 0, lpf, Exf, xf, out);
    }
}

// Round 5
// 383.784 us; speedup vs baseline: 3.7138x; 1.0503x over previous
//
#include <hip/hip_runtime.h>

#define B_ 256
#define D_ 784
#define V_ 128
#define S_ 2
#define BD (B_ * D_)
#define KSPLIT 8
#define KC 98      // 784 / KSPLIT

__device__ __forceinline__ void get_params(const int* kiter, float& ss, float& bal) {
    int k = kiter[0] % 10;
    ss  = (k == 0) ? 0.5f : 0.1f;
    bal = (k == 0) ? 0.9f : 0.6f;
}

__device__ __forceinline__ double wave_red(double v) {
#pragma unroll
    for (int o = 32; o > 0; o >>= 1) v += __shfl_down(v, o, 64);
    return v;
}

// ---------------------------------------------------------------------------
// split-K GEMM with on-the-fly Wsym and int->float A conversion:
//   Cpart[kz][b][d] = sum_{k in slice} float(A[b][k]) * 0.5*(W[k][d]+W[d][k])
// 64x64 tiles, kc=16 (float4 LDS reads), KSPLIT=8 (98 K each). Deterministic.
// ---------------------------------------------------------------------------
__global__ __launch_bounds__(256) void gemm_splitk(
    const int* __restrict__ Aint, const float* __restrict__ W,
    float* __restrict__ Cp)
{
    const int bt = blockIdx.x, dt = blockIdx.y, kz = blockIdx.z;
    const int tid = threadIdx.x;
    const int k0 = kz * KC, kend = k0 + KC;

    __shared__ float As[64][20];   // [row][kk], pad 20 -> 80B row stride, 16B aligned
    __shared__ float Ws[16][68];   // [kk][col], pad 68 -> 272B row stride, 16B aligned

    const int tx = tid & 15, ty = tid >> 4;
    const int arow = tid >> 2, ac0 = (tid & 3) * 4;
    const int wrow = tid >> 4, wc0 = (tid & 15) * 4;

    float acc[4][4] = {};

    for (int kb = k0; kb < kend; kb += 16) {
        // stage A (int -> float)
#pragma unroll
        for (int c = 0; c < 4; ++c) {
            int k = kb + ac0 + c;
            As[arow][ac0 + c] = (k < kend) ? (float)Aint[(bt * 64 + arow) * D_ + k] : 0.f;
        }
        // stage Wsym = 0.5*(W[k][d] + W[d][k])  (same arithmetic as init_k before)
#pragma unroll
        for (int c = 0; c < 4; ++c) {
            int k = kb + wrow;
            int d = dt * 64 + wc0 + c;
            Ws[wrow][wc0 + c] = (k < kend && d < D_)
                ? 0.5f * (W[k * D_ + d] + W[d * D_ + k]) : 0.f;
        }
        __syncthreads();
#pragma unroll
        for (int kk = 0; kk < 16; kk += 4) {
            float va[4][4], vw[4][4];
#pragma unroll
            for (int i = 0; i < 4; ++i) {
                float4 t = *(const float4*)&As[ty * 4 + i][kk];
                va[i][0] = t.x; va[i][1] = t.y; va[i][2] = t.z; va[i][3] = t.w;
            }
#pragma unroll
            for (int m = 0; m < 4; ++m) {
                float4 t = *(const float4*)&Ws[kk + m][tx * 4];
                vw[m][0] = t.x; vw[m][1] = t.y; vw[m][2] = t.z; vw[m][3] = t.w;
            }
#pragma unroll
            for (int m = 0; m < 4; ++m)
#pragma unroll
                for (int i = 0; i < 4; ++i)
#pragma unroll
                    for (int j = 0; j < 4; ++j)
                        acc[i][j] = fmaf(va[i][m], vw[m][j], acc[i][j]);
        }
        __syncthreads();
    }

#pragma unroll
    for (int i = 0; i < 4; ++i) {
        int bb = bt * 64 + ty * 4 + i;
#pragma unroll
        for (int j = 0; j < 4; ++j) {
            int d = dt * 64 + tx * 4 + j;
            if (d < D_) Cp[(size_t)kz * BD + (size_t)bb * D_ + d] = acc[i][j];
        }
    }
}

// ---------------------------------------------------------------------------
// forward: fused g-reduce + windowed categorical + lse. Window drop<=30
// (argmax needs 16.45 by gumbel range; lse tail < 1.2e-11 rel) => span <= 12
// values <= 4 quads. Gumbel read as up-to-4 float4 loads issued up-front.
// ---------------------------------------------------------------------------
__global__ __launch_bounds__(832) void forward_k(
    const int* __restrict__ xin, const float* __restrict__ gpart,
    const float* __restrict__ bvec, const float* __restrict__ gumbel,
    const int* __restrict__ kiter, int s,
    int* __restrict__ x_delta, double* __restrict__ lpf, double* __restrict__ Exf)
{
    const int b = blockIdx.x, tid = threadIdx.x;
    float ss, bal; get_params(kiter, ss, bal);
    const float c2 = 0.5f / ss;

    double lp_acc = 0.0, e_acc = 0.0;

    if (tid < D_) {
        const int d = tid, bd = b * D_ + d;
        const int xi = xin[bd];
        const float xfv = (float)xi;

        float gv = 0.f;
#pragma unroll
        for (int p = 0; p < KSPLIT; ++p) gv += gpart[(size_t)p * BD + bd];
        gv += bvec[d];

        const float a1 = bal * gv;
        const float v0 = xfv + a1 * ss;
        int vm = (int)rintf(v0); vm = min(127, max(0, vm));
        const float dmv = v0 - (float)vm;
        const float Reff = sqrtf(30.0f / c2 + dmv * dmv);
        int lo = max(0, (int)ceilf(v0 - Reff));
        int hi = min(127, (int)floorf(v0 + Reff));
        lo = min(lo, vm); hi = max(hi, vm);

        const float dvm = (float)vm - xfv;
        const float mL = dvm * fmaf(-c2, dvm, a1);   // exact max logit (concavity)

        const float4* __restrict__ gq =
            (const float4*)(gumbel + (((size_t)s * B_ + b) * D_ + d) * V_);
        const int q0 = lo >> 2, qh = hi >> 2;        // qh - q0 <= 3
        float4 quad[4];
#pragma unroll
        for (int j = 0; j < 4; ++j) quad[j] = gq[min(q0 + j, qh)];

        float best = -1e30f; int imax = vm;
        float sum0 = 0.f, sum1 = 0.f;
#pragma unroll
        for (int j = 0; j < 4; ++j) {
            const int qi = q0 + j;
            const bool qok = qi <= qh;
            const float qs[4] = {quad[j].x, quad[j].y, quad[j].z, quad[j].w};
#pragma unroll
            for (int c = 0; c < 4; ++c) {
                int v = 4 * qi + c;
                bool ok = qok && v >= lo && v <= hi;
                float dv = (float)v - xfv;
                float lg = dv * fmaf(-c2, dv, a1);
                float y = ok ? (lg + qs[c]) : -1e30f;
                if (y > best) { best = y; imax = v; }   // ascending v, strict >: np.argmax
                float e = expf(lg - mL);
                if (c & 1) sum1 += ok ? e : 0.f; else sum0 += ok ? e : 0.f;
            }
        }
        float lse = mL + logf(sum0 + sum1);
        float dvc = (float)imax - xfv;
        float lch = dvc * fmaf(-c2, dvc, a1);
        lp_acc = (double)(lch - lse);
        e_acc  = (double)xfv * ((double)gv + (double)bvec[d]);
        x_delta[bd] = imax;
    }

    __shared__ double wred[13];
    const int lane = tid & 63, wv = tid >> 6;
    double t = wave_red(lp_acc);
    if (lane == 0) wred[wv] = t;
    __syncthreads();
    if (tid == 0) { double sm = 0; for (int i = 0; i < 13; ++i) sm += wred[i]; lpf[b] = sm; }
    __syncthreads();
    t = wave_red(e_acc);
    if (lane == 0) wred[wv] = t;
    __syncthreads();
    if (tid == 0) { double sm = 0; for (int i = 0; i < 13; ++i) sm += wred[i]; Exf[b] = sm; }
}

// ---------------------------------------------------------------------------
// reverse: fused g-reduce + windowed lse + MH accept + x update + output.
// ---------------------------------------------------------------------------
__global__ __launch_bounds__(832) void reverse_k(
    const int* __restrict__ xin, int* __restrict__ x_cur,
    const int* __restrict__ x_delta,
    const float* __restrict__ gpart, const float* __restrict__ bvec,
    const float* __restrict__ u, const int* __restrict__ kiter,
    int s, int last, const double* __restrict__ lpf, const double* __restrict__ Exf,
    float* __restrict__ out)
{
    const int b = blockIdx.x, tid = threadIdx.x;
    float ss, bal; get_params(kiter, ss, bal);
    const float c2 = 0.5f / ss;

    double lp_acc = 0.0, e_acc = 0.0;

    if (tid < D_) {
        const int d = tid, bd = b * D_ + d;
        const int xi = xin[bd];
        const int xd = x_delta[bd];
        const float xdv = (float)xd;

        float gv = 0.f;
#pragma unroll
        for (int p = 0; p < KSPLIT; ++p) gv += gpart[(size_t)p * BD + bd];
        gv += bvec[d];

        const float a1 = bal * gv;
        const float v0 = xdv + a1 * ss;
        int vm = (int)rintf(v0); vm = min(127, max(0, vm));
        const float dmv = v0 - (float)vm;
        const float Reff = sqrtf(30.0f / c2 + dmv * dmv);
        int lo = max(0, (int)ceilf(v0 - Reff));
        int hi = min(127, (int)floorf(v0 + Reff));
        lo = min(lo, vm); hi = max(hi, vm);

        const float dvm = (float)vm - xdv;
        const float mL = dvm * fmaf(-c2, dvm, a1);
        float sum0 = 0.f, sum1 = 0.f;
#pragma unroll
        for (int j = 0; j < 16; ++j) {       // span <= 12, predicated, full ILP
            int v = lo + j;
            bool ok = v <= hi;
            float dv = (float)v - xdv;
            float lg = dv * fmaf(-c2, dv, a1);
            float e = expf(lg - mL);
            if (j & 1) sum1 += ok ? e : 0.f; else sum0 += ok ? e : 0.f;
        }
        float lse = mL + logf(sum0 + sum1);
        float dvc = (float)xi - xdv;                 // logp_d gathered at x_cur
        float lch = dvc * fmaf(-c2, dvc, a1);
        lp_acc = (double)(lch - lse);
        e_acc  = (double)xdv * ((double)gv + (double)bvec[d]);
    }

    __shared__ double wred[13];
    __shared__ int accept_s;
    __shared__ float la_s;
    const int lane = tid & 63, wv = tid >> 6;

    double t = wave_red(lp_acc);
    if (lane == 0) wred[wv] = t;
    __syncthreads();
    double lpr = 0;
    if (tid == 0) { for (int i = 0; i < 13; ++i) lpr += wred[i]; }
    __syncthreads();
    t = wave_red(e_acc);
    if (lane == 0) wred[wv] = t;
    __syncthreads();
    if (tid == 0) {
        double exd = 0; for (int i = 0; i < 13; ++i) exd += wred[i];
        double la = 0.5 * (exd - Exf[b]) + lpr - lpf[b];
        accept_s = (exp(la) > (double)u[s * B_ + b]) ? 1 : 0;
        la_s = (float)la;
    }
    __syncthreads();

    const int acc = accept_s;
    if (tid < D_) {
        const int bd = b * D_ + tid;
        int xn = acc ? x_delta[bd] : xin[bd];
        x_cur[bd] = xn;
        if (last) out[bd] = (float)xn;
    }
    if (last && tid == 0) out[BD + b] = la_s;
}

// ---------------------------------------------------------------------------
extern "C" void kernel_launch(void* const* d_in, const int* in_sizes, int n_in,
                              void* d_out, int out_size, void* d_ws, size_t ws_size,
                              hipStream_t stream)
{
    const int*   x     = (const int*)d_in[0];
    const float* W     = (const float*)d_in[1];
    const float* bv    = (const float*)d_in[2];
    const float* gum   = (const float*)d_in[3];
    const float* u     = (const float*)d_in[4];
    const int*   kiter = (const int*)d_in[5];
    float* out = (float*)d_out;

    char* w = (char*)d_ws;
    size_t off = 0;
    auto carve = [&](size_t bytes) { void* p = w + off; off += (bytes + 511) & ~511ull; return p; };
    int*    x_cur   = (int*)   carve((size_t)BD * 4);
    int*    x_delta = (int*)   carve((size_t)BD * 4);
    float*  gpart   = (float*) carve((size_t)KSPLIT * BD * 4);
    double* lpf     = (double*)carve(B_ * 8);
    double* Exf     = (double*)carve(B_ * 8);
    (void)ws_size; (void)in_sizes; (void)n_in; (void)out_size;

    for (int s = 0; s < S_; ++s) {
        const int* xin = (s == 0) ? x : x_cur;   // no init kernel: read x directly at s=0
        gemm_splitk<<<dim3(4, 13, KSPLIT), 256, 0, stream>>>(xin, W, gpart);
        forward_k<<<B_, 832, 0, stream>>>(xin, gpart, bv, gum, kiter, s,
                                          x_delta, lpf, Exf);
        gemm_splitk<<<dim3(4, 13, KSPLIT), 256, 0, stream>>>(x_delta, W, gpart);
        reverse_k<<<B_, 832, 0, stream>>>(xin, x_cur, x_delta, gpart, bv, u, kiter, s,
                                          (s == S_ - 1) ? 1 : 0, lpf, Exf, out);
    }
}